// Round 7
// baseline (264.207 us; speedup 1.0000x reference)
//
#include <hip/hip_runtime.h>

#define STEPS 30
#define HID 32
#define TPB 256
#define EPB 256                  // 4 waves x 2 groups x 32 elems: 2 chains per wave (ILP)
#define LDS_STRIDE (STEPS + 1)   // 31: odd stride -> conflict-free per-element column reads

typedef float f32x16 __attribute__((ext_vector_type(16)));
typedef __fp16 h8 __attribute__((ext_vector_type(8)));
typedef unsigned int u32x4 __attribute__((ext_vector_type(4)));

// v_cvt_pkrtz_f16_f32 -> packed (lo=x, hi=y) as one 32-bit reg
static __device__ __forceinline__ unsigned int pkrtz_u32(float x, float y) {
    return __builtin_bit_cast(unsigned int, __builtin_amdgcn_cvt_pkrtz(x, y));
}

__global__ __launch_bounds__(TPB, 2) void hedge_kernel(
    const float* __restrict__ S,
    const float* __restrict__ W1,
    const float* __restrict__ b1,
    const float* __restrict__ W2,
    const float* __restrict__ b2,
    const float* __restrict__ a_init,
    float* __restrict__ out)
{
    __shared__ float tile[EPB * LDS_STRIDE];   // 256*31*4 = 31744 B
    const int tid  = threadIdx.x;
    const int lane = tid & 63;
    const int wv   = tid >> 6;                 // wave id 0..3, owns elems 64*wv..64*wv+63
    const long long base = (long long)blockIdx.x * (EPB * STEPS);

    // ---- Stage S tile (256 elems x 30 steps) coalesced via float2 into padded LDS ----
    const float2* S2 = (const float2*)(S + base);
    #pragma unroll
    for (int k = 0; k < (EPB * STEPS) / (2 * TPB); ++k) {   // 15 iters
        int i2 = tid + k * TPB;            // float2 index in [0, 3840)
        float2 v = S2[i2];
        int row = i2 / 15;                 // = (2*i2)/30
        int col = 2 * (i2 - row * 15);     // even, <= 28: pair stays within a row
        float* p = &tile[row * LDS_STRIDE + col];
        p[0] = v.x; p[1] = v.y;
    }

    // ---- MFMA_A fragment (constant): W1^aug (32 units x K=16), biases in k0 row.
    //      A layout: row m = lane&31, k = (lane>>5)*8 + {0..7}.
    //      Lanes<32 hold k0..3 = (wb, wa, wc, we); all other k are 0 -> B garbage slots
    //      are harmless, and ONLY lanes<32 need valid (s,d,h). ----
    const int j = lane & 31;
    u32x4 av = {0u, 0u, 0u, 0u};
    if (lane < 32) {
        av[0] = pkrtz_u32(b1[j], W1[0 * HID + j]);          // k0=bias-row(1), k1=s
        av[1] = pkrtz_u32(W1[1 * HID + j], W1[2 * HID + j]); // k2=d, k3=h
    }
    const h8 afrag = __builtin_bit_cast(h8, av);

    // ---- MFMA_B fragments (constant): matrix row 0 = W2 permuted to match z's
    //      register order; all other rows 0. z reg r of a lane holds P row
    //      (r&3) + 8*(r>>2) + 4*(lane>>5); B-fragment k-slot e <- z reg e, with
    //      k0..7 supplied by lanes<32 (rbase 0) and k8..15 by lanes>=32 (rbase 4).
    //      So lane (lane&31)==0 holds W2[perm(e)] in its 8 k-slots. ----
    u32x4 avB1 = {0u, 0u, 0u, 0u}, avB2 = {0u, 0u, 0u, 0u};
    if ((lane & 31) == 0) {
        const int rb = 4 * (lane >> 5);    // 0 for lane 0, 4 for lane 32
        avB1[0] = pkrtz_u32(W2[0 + rb],  W2[1 + rb]);    // z regs 0..1 -> rows rb+{0,1}
        avB1[1] = pkrtz_u32(W2[2 + rb],  W2[3 + rb]);    // rows rb+{2,3}
        avB1[2] = pkrtz_u32(W2[8 + rb],  W2[9 + rb]);    // rows rb+{8,9}
        avB1[3] = pkrtz_u32(W2[10 + rb], W2[11 + rb]);   // rows rb+{10,11}
        avB2[0] = pkrtz_u32(W2[16 + rb], W2[17 + rb]);   // z regs 8..15 -> rows rb+16..
        avB2[1] = pkrtz_u32(W2[18 + rb], W2[19 + rb]);
        avB2[2] = pkrtz_u32(W2[24 + rb], W2[25 + rb]);
        avB2[3] = pkrtz_u32(W2[26 + rb], W2[27 + rb]);
    }
    const h8 afragB1 = __builtin_bit_cast(h8, avB1);
    const h8 afragB2 = __builtin_bit_cast(h8, avB2);

    const float bias2 = b2[0];
    const float d_init = a_init[0];
    float dA = d_init, hA = 0.0f;              // chain A state (fp32)
    float dB = d_init, hB = 0.0f;              // chain B state (fp32)
    const f32x16 zero16 = {0.f};               // loop-invariant C operand
    __syncthreads();

    // ---- Recurrence: one wave = 2 independent 32-element groups, interleaved.
    //      Per chain-step: MFMA_A (layer 1) -> relu+pack -> MFMA_B1||B2 (layer 2).
    //      d lands in reg0 of lanes<32 -- exactly the lanes that feed the next B
    //      fragment and write the output. No cross-lane ops on the d-chain. ----
    const int erow = 64 * wv + (lane & 31);
    float* myA = &tile[erow * LDS_STRIDE];
    float* myB = &tile[(erow + 32) * LDS_STRIDE];
    #pragma unroll
    for (int t = 0; t < STEPS; ++t) {
        const float sA = myA[t];               // bank (t - lane) mod 32: conflict-free
        const float sB = myB[t];

        u32x4 bvA, bvB;
        bvA[0] = pkrtz_u32(1.0f, sA);          // k0=1 (bias), k1=s
        bvA[1] = pkrtz_u32(dA, hA);            // k2=d, k3=h
        bvA[2] = bvA[0]; bvA[3] = bvA[1];      // dead slots (A zeros)
        bvB[0] = pkrtz_u32(1.0f, sB);
        bvB[1] = pkrtz_u32(dB, hB);
        bvB[2] = bvB[0]; bvB[3] = bvB[1];

        const f32x16 PA = __builtin_amdgcn_mfma_f32_32x32x16_f16(
            afrag, __builtin_bit_cast(h8, bvA), zero16, 0, 0, 0);
        const f32x16 PB = __builtin_amdgcn_mfma_f32_32x32x16_f16(
            afrag, __builtin_bit_cast(h8, bvB), zero16, 0, 0, 0);

        // relu in f32 (exact reference order), then pack to z fragments
        u32x4 zA1, zA2, zB1, zB2;
        #pragma unroll
        for (int i = 0; i < 4; ++i) {
            zA1[i] = pkrtz_u32(fmaxf(PA[2*i + 0], 0.f), fmaxf(PA[2*i + 1], 0.f));
            zA2[i] = pkrtz_u32(fmaxf(PA[2*i + 8], 0.f), fmaxf(PA[2*i + 9], 0.f));
            zB1[i] = pkrtz_u32(fmaxf(PB[2*i + 0], 0.f), fmaxf(PB[2*i + 1], 0.f));
            zB2[i] = pkrtz_u32(fmaxf(PB[2*i + 8], 0.f), fmaxf(PB[2*i + 9], 0.f));
        }

        // layer 2 on the matrix pipe: row 0 = W2^T z (two K=16 halves, parallel)
        const f32x16 yA1 = __builtin_amdgcn_mfma_f32_32x32x16_f16(
            afragB1, __builtin_bit_cast(h8, zA1), zero16, 0, 0, 0);
        const f32x16 yA2 = __builtin_amdgcn_mfma_f32_32x32x16_f16(
            afragB2, __builtin_bit_cast(h8, zA2), zero16, 0, 0, 0);
        const f32x16 yB1 = __builtin_amdgcn_mfma_f32_32x32x16_f16(
            afragB1, __builtin_bit_cast(h8, zB1), zero16, 0, 0, 0);
        const f32x16 yB2 = __builtin_amdgcn_mfma_f32_32x32x16_f16(
            afragB2, __builtin_bit_cast(h8, zB2), zero16, 0, 0, 0);

        const float dnA = (yA1[0] + yA2[0]) + bias2;   // valid in lanes<32 (row 0)
        const float dnB = (yB1[0] + yB2[0]) + bias2;   // hi lanes: harmless garbage
        hA = fmaf(0.2f, dnA, 0.8f * hA);
        hB = fmaf(0.2f, dnB, 0.8f * hB);
        dA = dnA;
        dB = dnB;
        if (lane < 32) {                       // only lo lanes hold real d
            myA[t] = dnA;                      // S[t] consumed; slot reused for output
            myB[t] = dnB;
        }
    }
    __syncthreads();

    // ---- Dump outputs coalesced via float2 (same flat layout as S) ----
    float2* O2 = (float2*)(out + base);
    #pragma unroll
    for (int k = 0; k < (EPB * STEPS) / (2 * TPB); ++k) {   // 15 iters
        int i2 = tid + k * TPB;
        int row = i2 / 15;
        int col = 2 * (i2 - row * 15);
        const float* p = &tile[row * LDS_STRIDE + col];
        O2[i2] = make_float2(p[0], p[1]);
    }
}

extern "C" void kernel_launch(void* const* d_in, const int* in_sizes, int n_in,
                              void* d_out, int out_size, void* d_ws, size_t ws_size,
                              hipStream_t stream) {
    const float* S      = (const float*)d_in[0];
    const float* W1     = (const float*)d_in[1];
    const float* b1     = (const float*)d_in[2];
    const float* W2     = (const float*)d_in[3];
    const float* b2     = (const float*)d_in[4];
    const float* a_init = (const float*)d_in[5];
    float* out = (float*)d_out;

    const int batch = in_sizes[0] / STEPS;    // 1048576
    const int grid  = batch / EPB;            // 4096 blocks of 256 elements
    hedge_kernel<<<grid, TPB, 0, stream>>>(S, W1, b1, W2, b2, a_init, out);
}

// Round 9
// 260.799 us; speedup vs baseline: 1.0131x; 1.0131x over previous
//
#include <hip/hip_runtime.h>

#define STEPS 30
#define HID 32
#define TPB 256
#define EPB 256                  // 4 waves x 2 groups x 32 elems: 2 chains per wave (ILP)
#define LDS_STRIDE (STEPS + 1)   // 31: odd stride -> conflict-free per-element column reads

typedef float f32x16 __attribute__((ext_vector_type(16)));
typedef __fp16 h8 __attribute__((ext_vector_type(8)));
typedef unsigned int u32x4 __attribute__((ext_vector_type(4)));

// v_cvt_pkrtz_f16_f32 -> packed (lo=x, hi=y) as one 32-bit reg
static __device__ __forceinline__ unsigned int pkrtz_u32(float x, float y) {
    return __builtin_bit_cast(unsigned int, __builtin_amdgcn_cvt_pkrtz(x, y));
}

// Half-wave pair sum via v_permlane32_swap_b32 (VALU, ~4 cyc) instead of a DS
// round-trip (~60 cyc). Two "+v" outputs force DISTINCT physical registers
// (round-8 bug: builtin with identical operands collapsed to a self-swap).
// HW exchanges vdst's high half with src's low half: a={u_lo,u_lo},
// b={u_hi,u_hi} (or mirrored) -> a+b = part[lane]+part[lane^32] in all lanes.
static __device__ __forceinline__ float halfsum(float part) {
    float a = part, b = part;
    asm("v_permlane32_swap_b32 %0, %1" : "+v"(a), "+v"(b));
    return a + b;
}

__global__ __launch_bounds__(TPB, 4) void hedge_kernel(
    const float* __restrict__ S,
    const float* __restrict__ W1,
    const float* __restrict__ b1,
    const float* __restrict__ W2,
    const float* __restrict__ b2,
    const float* __restrict__ a_init,
    float* __restrict__ out)
{
    __shared__ float tile[EPB * LDS_STRIDE];   // 256*31*4 = 31744 B
    const int tid  = threadIdx.x;
    const int lane = tid & 63;
    const int wv   = tid >> 6;                 // wave id 0..3, owns elems 64*wv..64*wv+63
    const long long base = (long long)blockIdx.x * (EPB * STEPS);

    // ---- Stage S tile (256 elems x 30 steps) coalesced via float2 into padded LDS ----
    const float2* S2 = (const float2*)(S + base);
    #pragma unroll
    for (int k = 0; k < (EPB * STEPS) / (2 * TPB); ++k) {   // 15 iters
        int i2 = tid + k * TPB;            // float2 index in [0, 3840)
        float2 v = S2[i2];
        int row = i2 / 15;                 // = (2*i2)/30
        int col = 2 * (i2 - row * 15);     // even, <= 28: pair stays within a row
        float* p = &tile[row * LDS_STRIDE + col];
        p[0] = v.x; p[1] = v.y;
    }

    // ---- A fragment (constant): W1^aug (32 units x K=16), biases in k0 row.
    //      mfma_f32_32x32x16_f16 A layout: row m = lane&31, k = (lane>>5)*8 + {0..7}.
    //      Lanes<32 hold k0..3 = (wb, wa, wc, we); all other k are 0 -> B garbage slots
    //      are harmless. ----
    const int j = lane & 31;
    u32x4 av = {0u, 0u, 0u, 0u};
    if (lane < 32) {
        av[0] = pkrtz_u32(b1[j], W1[0 * HID + j]);           // k0=bias-row(1), k1=s
        av[1] = pkrtz_u32(W1[1 * HID + j], W1[2 * HID + j]); // k2=d, k3=h
    }
    const h8 afrag = __builtin_bit_cast(h8, av);

    // ---- Per-lane W2 slice matching the C/D row map:
    //      row(reg r) = (r&3) + 8*(r>>2) + 4*(lane>>5) ----
    const int rbase = 4 * (lane >> 5);
    float w2r[16];
    #pragma unroll
    for (int r = 0; r < 16; ++r)
        w2r[r] = W2[(r & 3) + 8 * (r >> 2) + rbase];

    const float bias2 = b2[0];
    const float d_init = a_init[0];
    float dA = d_init, hA = 0.0f;              // chain A state (fp32)
    float dB = d_init, hB = 0.0f;              // chain B state (fp32)
    const f32x16 zero16 = {0.f};               // loop-invariant C operand
    __syncthreads();

    // ---- Recurrence: one wave = 2 independent 32-element groups, interleaved.
    //      Critical path per step: pkrtz -> MFMA -> 4-deep fma tree -> permlane sum.
    //      No DS on the d-chain. ----
    const int erow = 64 * wv + (lane & 31);
    float* myA = &tile[erow * LDS_STRIDE];
    float* myB = &tile[(erow + 32) * LDS_STRIDE];
    #pragma unroll
    for (int t = 0; t < STEPS; ++t) {
        const float sA = myA[t];               // bank (t - lane) mod 32: conflict-free
        const float sB = myB[t];

        u32x4 bvA, bvB;
        bvA[0] = pkrtz_u32(1.0f, sA);          // k0=1 (bias), k1=s
        bvA[1] = pkrtz_u32(dA, hA);            // k2=d, k3=h
        bvA[2] = 0u; bvA[3] = 0u;              // dead slots (A rows k4..15 are zero)
        bvB[0] = pkrtz_u32(1.0f, sB);
        bvB[1] = pkrtz_u32(dB, hB);
        bvB[2] = 0u; bvB[3] = 0u;

        const f32x16 PA = __builtin_amdgcn_mfma_f32_32x32x16_f16(
            afrag, __builtin_bit_cast(h8, bvA), zero16, 0, 0, 0);
        const f32x16 PB = __builtin_amdgcn_mfma_f32_32x32x16_f16(
            afrag, __builtin_bit_cast(h8, bvB), zero16, 0, 0, 0);

        // layer 2: 4 independent 4-deep fma chains per chain (latency 4x4 cyc)
        float a0 = 0.f, a1 = 0.f, a2 = 0.f, a3 = 0.f;
        float b0 = 0.f, b1v = 0.f, b2v = 0.f, b3 = 0.f;
        #pragma unroll
        for (int r = 0; r < 16; r += 4) {
            a0  = fmaf(w2r[r + 0], fmaxf(PA[r + 0], 0.f), a0);
            a1  = fmaf(w2r[r + 1], fmaxf(PA[r + 1], 0.f), a1);
            a2  = fmaf(w2r[r + 2], fmaxf(PA[r + 2], 0.f), a2);
            a3  = fmaf(w2r[r + 3], fmaxf(PA[r + 3], 0.f), a3);
            b0  = fmaf(w2r[r + 0], fmaxf(PB[r + 0], 0.f), b0);
            b1v = fmaf(w2r[r + 1], fmaxf(PB[r + 1], 0.f), b1v);
            b2v = fmaf(w2r[r + 2], fmaxf(PB[r + 2], 0.f), b2v);
            b3  = fmaf(w2r[r + 3], fmaxf(PB[r + 3], 0.f), b3);
        }
        const float partA = (a0 + a1) + (a2 + a3);   // this half-wave's 16 units
        const float partB = (b0 + b1v) + (b2v + b3);
        const float dnA = bias2 + halfsum(partA);    // all lanes: full d_t (VALU swap)
        const float dnB = bias2 + halfsum(partB);
        hA = fmaf(0.2f, dnA, 0.8f * hA);
        hB = fmaf(0.2f, dnB, 0.8f * hB);
        dA = dnA;
        dB = dnB;
        if (lane < 32) {                       // halves hold identical dn: write once
            myA[t] = dnA;                      // S[t] consumed; slot reused for output
            myB[t] = dnB;
        }
    }
    __syncthreads();

    // ---- Dump outputs coalesced via float2 (same flat layout as S) ----
    float2* O2 = (float2*)(out + base);
    #pragma unroll
    for (int k = 0; k < (EPB * STEPS) / (2 * TPB); ++k) {   // 15 iters
        int i2 = tid + k * TPB;
        int row = i2 / 15;
        int col = 2 * (i2 - row * 15);
        const float* p = &tile[row * LDS_STRIDE + col];
        O2[i2] = make_float2(p[0], p[1]);
    }
}

extern "C" void kernel_launch(void* const* d_in, const int* in_sizes, int n_in,
                              void* d_out, int out_size, void* d_ws, size_t ws_size,
                              hipStream_t stream) {
    const float* S      = (const float*)d_in[0];
    const float* W1     = (const float*)d_in[1];
    const float* b1     = (const float*)d_in[2];
    const float* W2     = (const float*)d_in[3];
    const float* b2     = (const float*)d_in[4];
    const float* a_init = (const float*)d_in[5];
    float* out = (float*)d_out;

    const int batch = in_sizes[0] / STEPS;    // 1048576
    const int grid  = batch / EPB;            // 4096 blocks of 256 elements
    hedge_kernel<<<grid, TPB, 0, stream>>>(S, W1, b1, W2, b2, a_init, out);
}